// Round 1
// baseline (401.612 us; speedup 1.0000x reference)
//
#include <hip/hip_runtime.h>

// PillarMaxPooling: gather-center -> (11->32) matmul -> BN(train stats) -> ReLU -> segment-max
// N=800k points, M=120k pillars, C=32 channels.
// Layout: channel-per-thread (c = tid&31). W1 column in registers; point data
// broadcast across the 32 lanes sharing a point.

#define CMLP 32
#define BN_EPS 1e-3f
#define PSIZE 0.075f
#define XMIN -54.0f
#define YMIN -54.0f
#define CZ   -1.0f   // 0.5*(Z_MIN+Z_MAX) = 0.5*(-5+3)

__device__ __forceinline__ float compute_h(
    const float* __restrict__ xyz, const float* __restrict__ ptf,
    const int* __restrict__ pil, const int* __restrict__ sidx,
    const float* w, int p, int* m_out) {
  int m = sidx[p];
  *m_out = m;
  float px = (float)pil[3 * m + 2];
  float py = (float)pil[3 * m + 1];
  float cx = fmaf(px + 0.5f, PSIZE, XMIN);
  float cy = fmaf(py + 0.5f, PSIZE, YMIN);
  float x = xyz[3 * p], y = xyz[3 * p + 1], z = xyz[3 * p + 2];
  float h = (x - cx) * w[0];
  h = fmaf(y - cy, w[1], h);
  h = fmaf(z - CZ, w[2], h);
  h = fmaf(x, w[3], h);
  h = fmaf(y, w[4], h);
  h = fmaf(z, w[5], h);
#pragma unroll
  for (int k = 0; k < 5; k++) h = fmaf(ptf[5 * p + k], w[6 + k], h);
  return h;
}

__global__ void __launch_bounds__(256) stats_kernel(
    const float* __restrict__ xyz, const float* __restrict__ ptf,
    const float* __restrict__ W1, const int* __restrict__ pil,
    const int* __restrict__ sidx, float* __restrict__ stats, int npairs) {
  const int c = threadIdx.x & 31;
  float w[11];
#pragma unroll
  for (int k = 0; k < 11; k++) w[k] = W1[k * CMLP + c];
  float s = 0.f, ss = 0.f;
  int stride = gridDim.x * blockDim.x;
  for (int i = blockIdx.x * blockDim.x + threadIdx.x; i < npairs; i += stride) {
    int p = i >> 5, m;
    float h = compute_h(xyz, ptf, pil, sidx, w, p, &m);
    s += h;
    ss = fmaf(h, h, ss);
  }
  // lanes L and L+32 hold the same channel c -> combine, then 1 atomic per channel per wave
  s += __shfl_xor(s, 32);
  ss += __shfl_xor(ss, 32);
  if ((threadIdx.x & 63) < 32) {
    atomicAdd(&stats[c], s);
    atomicAdd(&stats[CMLP + c], ss);
  }
}

__global__ void finalize_kernel(const float* __restrict__ gamma,
                                const float* __restrict__ beta,
                                float* __restrict__ stats, float invN) {
  int c = threadIdx.x;
  if (c < CMLP) {
    float mean = stats[c] * invN;
    float var = stats[CMLP + c] * invN - mean * mean;
    float sc = gamma[c] / sqrtf(var + BN_EPS);
    stats[64 + c] = sc;            // scale
    stats[96 + c] = beta[c] - mean * sc;  // bias
  }
}

__global__ void __launch_bounds__(256) scatter_kernel(
    const float* __restrict__ xyz, const float* __restrict__ ptf,
    const float* __restrict__ W1, const int* __restrict__ pil,
    const int* __restrict__ sidx, const float* __restrict__ scale_bias,
    float* __restrict__ out, int npairs) {
  const int c = threadIdx.x & 31;
  float w[11];
#pragma unroll
  for (int k = 0; k < 11; k++) w[k] = W1[k * CMLP + c];
  float sc = scale_bias[c];
  float bi = scale_bias[CMLP + c];
  int stride = gridDim.x * blockDim.x;
  for (int i = blockIdx.x * blockDim.x + threadIdx.x; i < npairs; i += stride) {
    int p = i >> 5, m;
    float h = compute_h(xyz, ptf, pil, sidx, w, p, &m);
    float v = fmaxf(fmaf(h, sc, bi), 0.f);
    // v >= 0 and out initialized to 0: int compare == float compare on non-negative floats
    atomicMax((int*)&out[m * CMLP + c], __float_as_int(v));
  }
}

extern "C" void kernel_launch(void* const* d_in, const int* in_sizes, int n_in,
                              void* d_out, int out_size, void* d_ws, size_t ws_size,
                              hipStream_t stream) {
  const float* xyz = (const float*)d_in[0];
  const float* ptf = (const float*)d_in[1];
  const float* W1 = (const float*)d_in[2];
  const float* gamma = (const float*)d_in[3];
  const float* beta = (const float*)d_in[4];
  const int* pil = (const int*)d_in[5];
  const int* sidx = (const int*)d_in[6];
  float* out = (float*)d_out;
  float* stats = (float*)d_ws;  // [0:32) sum, [32:64) sumsq, [64:96) scale, [96:128) bias

  int N = in_sizes[0] / 3;
  int npairs = N * CMLP;

  hipMemsetAsync(stats, 0, 64 * sizeof(float), stream);
  hipMemsetAsync(out, 0, (size_t)out_size * sizeof(float), stream);

  const int blocks = 2048, threads = 256;
  stats_kernel<<<blocks, threads, 0, stream>>>(xyz, ptf, W1, pil, sidx, stats, npairs);
  finalize_kernel<<<1, 64, 0, stream>>>(gamma, beta, stats, 1.0f / (float)N);
  scatter_kernel<<<blocks, threads, 0, stream>>>(xyz, ptf, W1, pil, sidx, stats + 64, out, npairs);
}

// Round 2
// 237.249 us; speedup vs baseline: 1.6928x; 1.6928x over previous
//
#include <hip/hip_runtime.h>

// PillarMaxPooling: gather-center -> (11->32) matmul -> BN(train stats) -> ReLU -> segment-max
// N=800k, M=120k, C=32.
// R2: LDS point-tile staging. Block = 256 points; phase 1 one thread per point
// loads its 11 features ONCE into LDS (row stride 12 floats = 48B, 16B-aligned,
// non-pow2 bank stride); phase 2 channel-per-thread (c=tid&31) reads rows via
// ds_read_b128 broadcast. Fixes R1's latency-bound 32x-redundant VMEM issue
// (250us stats @ 9% VALU, 1.9% HBM).

#define CMLP 32
#define BN_EPS 1e-3f
#define PSIZE 0.075f
#define XMIN -54.0f
#define YMIN -54.0f
#define CZ   -1.0f   // 0.5*(Z_MIN+Z_MAX)
#define TILE 256

__device__ __forceinline__ void stage_point(
    const float* __restrict__ xyz, const float* __restrict__ ptf,
    const int* __restrict__ pil, const int* __restrict__ sidx,
    float* __restrict__ feat, int* __restrict__ midx,
    int tid, int p, bool valid) {
  if (!valid) return;
  int m = sidx[p];
  float cx = fmaf((float)pil[3 * m + 2] + 0.5f, PSIZE, XMIN);
  float cy = fmaf((float)pil[3 * m + 1] + 0.5f, PSIZE, YMIN);
  float x = xyz[3 * p], y = xyz[3 * p + 1], z = xyz[3 * p + 2];
  float* f = &feat[tid * 12];
  f[0] = x - cx;
  f[1] = y - cy;
  f[2] = z - CZ;
  f[3] = x;
  f[4] = y;
  f[5] = z;
#pragma unroll
  for (int k = 0; k < 5; k++) f[6 + k] = ptf[5 * p + k];
  f[11] = 0.f;
  if (midx) midx[tid] = m;
}

__device__ __forceinline__ float dot11(const float* __restrict__ feat, int j,
                                       const float* w) {
  const float4* f4 = (const float4*)&feat[j * 12];
  float4 a = f4[0], b = f4[1], d = f4[2];
  float h = a.x * w[0];
  h = fmaf(a.y, w[1], h);
  h = fmaf(a.z, w[2], h);
  h = fmaf(a.w, w[3], h);
  h = fmaf(b.x, w[4], h);
  h = fmaf(b.y, w[5], h);
  h = fmaf(b.z, w[6], h);
  h = fmaf(b.w, w[7], h);
  h = fmaf(d.x, w[8], h);
  h = fmaf(d.y, w[9], h);
  h = fmaf(d.z, w[10], h);
  return h;
}

__global__ void __launch_bounds__(256) stats_kernel(
    const float* __restrict__ xyz, const float* __restrict__ ptf,
    const float* __restrict__ W1, const int* __restrict__ pil,
    const int* __restrict__ sidx, float* __restrict__ stats, int N) {
  __shared__ float feat[TILE * 12];
  __shared__ float red[2 * TILE];
  const int tid = threadIdx.x;
  const int c = tid & 31;
  const int grp = tid >> 5;  // 0..7
  float w[11];
#pragma unroll
  for (int k = 0; k < 11; k++) w[k] = W1[k * CMLP + c];

  const int base = blockIdx.x * TILE;
  const int cnt = min(TILE, N - base);
  stage_point(xyz, ptf, pil, sidx, feat, nullptr, tid, base + tid, tid < cnt);
  __syncthreads();

  float s = 0.f, ss = 0.f;
#pragma unroll 4
  for (int t = 0; t < TILE / 8; t++) {
    int j = grp + t * 8;
    if (j < cnt) {
      float h = dot11(feat, j, w);
      s += h;
      ss = fmaf(h, h, ss);
    }
  }
  __syncthreads();
  red[tid] = s;
  red[TILE + tid] = ss;
  __syncthreads();
  if (tid < 32) {
    float acc = 0.f;
#pragma unroll
    for (int g = 0; g < 8; g++) acc += red[tid + 32 * g];
    atomicAdd(&stats[tid], acc);
  } else if (tid < 64) {
    int cc = tid - 32;
    float acc = 0.f;
#pragma unroll
    for (int g = 0; g < 8; g++) acc += red[TILE + cc + 32 * g];
    atomicAdd(&stats[CMLP + cc], acc);
  }
}

__global__ void finalize_kernel(const float* __restrict__ gamma,
                                const float* __restrict__ beta,
                                float* __restrict__ stats, float invN) {
  int c = threadIdx.x;
  if (c < CMLP) {
    float mean = stats[c] * invN;
    float var = stats[CMLP + c] * invN - mean * mean;
    float sc = gamma[c] / sqrtf(var + BN_EPS);
    stats[64 + c] = sc;                   // scale
    stats[96 + c] = beta[c] - mean * sc;  // bias
  }
}

__global__ void __launch_bounds__(256) scatter_kernel(
    const float* __restrict__ xyz, const float* __restrict__ ptf,
    const float* __restrict__ W1, const int* __restrict__ pil,
    const int* __restrict__ sidx, const float* __restrict__ scale_bias,
    float* __restrict__ out, int N) {
  __shared__ float feat[TILE * 12];
  __shared__ int midx[TILE];
  const int tid = threadIdx.x;
  const int c = tid & 31;
  const int grp = tid >> 5;
  float w[11];
#pragma unroll
  for (int k = 0; k < 11; k++) w[k] = W1[k * CMLP + c];
  const float sc = scale_bias[c];
  const float bi = scale_bias[CMLP + c];

  const int base = blockIdx.x * TILE;
  const int cnt = min(TILE, N - base);
  stage_point(xyz, ptf, pil, sidx, feat, midx, tid, base + tid, tid < cnt);
  __syncthreads();

#pragma unroll 4
  for (int t = 0; t < TILE / 8; t++) {
    int j = grp + t * 8;
    if (j < cnt) {
      float h = dot11(feat, j, w);
      float v = fmaxf(fmaf(h, sc, bi), 0.f);
      int m = midx[j];
      // v >= 0, out zero-initialized: int order == float order on non-negatives
      atomicMax((int*)&out[m * CMLP + c], __float_as_int(v));
    }
  }
}

extern "C" void kernel_launch(void* const* d_in, const int* in_sizes, int n_in,
                              void* d_out, int out_size, void* d_ws, size_t ws_size,
                              hipStream_t stream) {
  const float* xyz = (const float*)d_in[0];
  const float* ptf = (const float*)d_in[1];
  const float* W1 = (const float*)d_in[2];
  const float* gamma = (const float*)d_in[3];
  const float* beta = (const float*)d_in[4];
  const int* pil = (const int*)d_in[5];
  const int* sidx = (const int*)d_in[6];
  float* out = (float*)d_out;
  float* stats = (float*)d_ws;  // [0:32) sum [32:64) sumsq [64:96) scale [96:128) bias

  int N = in_sizes[0] / 3;
  int blocks = (N + TILE - 1) / TILE;  // 3125

  hipMemsetAsync(stats, 0, 64 * sizeof(float), stream);
  hipMemsetAsync(out, 0, (size_t)out_size * sizeof(float), stream);

  stats_kernel<<<blocks, 256, 0, stream>>>(xyz, ptf, W1, pil, sidx, stats, N);
  finalize_kernel<<<1, 64, 0, stream>>>(gamma, beta, stats, 1.0f / (float)N);
  scatter_kernel<<<blocks, 256, 0, stream>>>(xyz, ptf, W1, pil, sidx, stats + 64, out, N);
}